// Round 3
// baseline (11622.330 us; speedup 1.0000x reference)
//
#include <hip/hip_runtime.h>

#define HID 64
#define TSTEPS 64
#define NTHREADS 1024
#define ROWS_PB 256

typedef __attribute__((ext_vector_type(8))) short bf16x8;
typedef __attribute__((ext_vector_type(8))) unsigned short u16x8;
typedef __attribute__((ext_vector_type(4))) float f32x4;

__device__ __forceinline__ float fast_exp2(float x) { return __builtin_amdgcn_exp2f(x); }
__device__ __forceinline__ float fast_rcp(float x)  { return __builtin_amdgcn_rcpf(x); }
#define LOG2E 1.44269504088896341f
__device__ __forceinline__ float sigmoidf_(float x) { return fast_rcp(1.0f + fast_exp2(-LOG2E * x)); }
__device__ __forceinline__ float tanhf_(float x)    { return 1.0f - 2.0f * fast_rcp(1.0f + fast_exp2(2.0f * LOG2E * x)); }

__device__ __forceinline__ unsigned short f2bf(float f) {   // RNE fp32->bf16
    unsigned u = __float_as_uint(f);
    u = u + 0x7fffu + ((u >> 16) & 1u);
    return (unsigned short)(u >> 16);
}
__device__ __forceinline__ float bfh(unsigned short h) { return __uint_as_float(((unsigned)h) << 16); }
__device__ __forceinline__ unsigned cvt_pk_bf16(float a, float b) {  // low16=bf(a), high16=bf(b)
    unsigned r;
    asm("v_cvt_pk_bf16_f32 %0, %1, %2" : "=v"(r) : "v"(a), "v"(b));
    return r;
}

// ---------------- LDS layout (bytes) ----------------
// [0,      65536)  xseq  : [t=64][row=256] f32
// [65536, 147456)  WA    : 16 tiles x 5 frags x 64 lanes x 16B  (A-operand frags)
//                  frag order per tile: 0=hi kc0, 1=hi kc1, 2=lo kc0, 3=lo kc1, 4=ext
// [147456, ...  )  mog   : m0 bf16[64] | m2 | m4 | m1pk u32[64] | m3pk u32[64] | wp f32[320]
// stem overlay: buf [256][68] f32 at 65536..135168 (before WA staging)
#define OFF_XSEQ 0
#define OFF_WA   65536
#define OFF_MOG  147456
#define OFF_STEM 65536
#define SMEM_TOTAL 149760

__global__ __launch_bounds__(NTHREADS, 4) void moglstm_mfma2(
    const float* __restrict__ x,
    const float* __restrict__ W1, const float* __restrict__ B1,
    const float* __restrict__ W2, const float* __restrict__ B2,
    const float* __restrict__ W3, const float* __restrict__ B3,
    const float* __restrict__ W4, const float* __restrict__ B4,
    const float* __restrict__ M0w, const float* __restrict__ M0b,
    const float* __restrict__ M1w, const float* __restrict__ M1b,
    const float* __restrict__ M2w, const float* __restrict__ M2b,
    const float* __restrict__ M3w, const float* __restrict__ M3b,
    const float* __restrict__ M4w, const float* __restrict__ M4b,
    const float* __restrict__ Wih, const float* __restrict__ Bih,
    const float* __restrict__ Whh, const float* __restrict__ Bhh,
    const float* __restrict__ Wp,  const float* __restrict__ Bp,
    float* __restrict__ out)
{
    __shared__ __align__(16) char smem[SMEM_TOTAL];
    float*  xseq = (float*)(smem + OFF_XSEQ);
    bf16x8* WA   = (bf16x8*)(smem + OFF_WA);
    float*  buf  = (float*)(smem + OFF_STEM);

    const int tid = threadIdx.x;
    const long rowbase = (long)blockIdx.x * ROWS_PB;

    // ---- stage mog tables (region disjoint from stem buffers) ----
    if (tid < 64) {
        unsigned short* m0 = (unsigned short*)(smem + OFF_MOG);
        m0[tid]       = f2bf(M0w[tid]);
        m0[64 + tid]  = f2bf(M2w[tid]);
        m0[128 + tid] = f2bf(M4w[tid]);
        unsigned* mp = (unsigned*)(smem + OFF_MOG + 384);
        mp[tid]      = (unsigned)f2bf(M1w[tid]) | ((unsigned)f2bf(M1b[tid]) << 16);
        mp[64 + tid] = (unsigned)f2bf(M3w[tid]) | ((unsigned)f2bf(M3b[tid]) << 16);
    }
    for (int i = tid; i < 320; i += NTHREADS)
        ((float*)(smem + OFF_MOG + 896))[i] = Wp[i];

    // ================= MLP stem =================
    // load x rows -> buf[256][68]
    for (int i = tid; i < ROWS_PB * 16; i += NTHREADS) {
        int r = i >> 4, c4 = i & 15;
        *(float4*)&buf[r * 68 + c4 * 4] = ((const float4*)x)[(rowbase + r) * 16 + c4];
    }
    __syncthreads();

    {
        const int sr = tid & 255;   // row
        const int sq = tid >> 8;    // quarter -> units sq*16..+15 (wave-uniform)
        const float* Ws[4] = {W1, W2, W3, W4};
        const float* Bs[4] = {B1, B2, B3, B4};
        float rin[HID];
        #pragma unroll
        for (int L = 0; L < 4; ++L) {
            #pragma unroll
            for (int k4 = 0; k4 < 16; ++k4) {
                float4 v = *(const float4*)&buf[sr * 68 + k4 * 4];
                rin[4*k4+0] = v.x; rin[4*k4+1] = v.y; rin[4*k4+2] = v.z; rin[4*k4+3] = v.w;
            }
            __syncthreads();
            const float* W = Ws[L];
            const float* Bb = Bs[L];
            #pragma unroll
            for (int jj4 = 0; jj4 < 4; ++jj4) {
                float o[4];
                #pragma unroll
                for (int e = 0; e < 4; ++e) {
                    int j = sq * 16 + jj4 * 4 + e;
                    float a = Bb[j];
                    const float4* wr = (const float4*)(W + j * 64);  // wave-uniform -> s_load
                    #pragma unroll
                    for (int k4 = 0; k4 < 16; ++k4) {
                        float4 w = wr[k4];
                        a += w.x*rin[4*k4] + w.y*rin[4*k4+1] + w.z*rin[4*k4+2] + w.w*rin[4*k4+3];
                    }
                    o[e] = fmaxf(a, 0.0f);
                }
                if (L < 3) {
                    *(float4*)&buf[sr * 68 + sq * 16 + jj4 * 4] = make_float4(o[0], o[1], o[2], o[3]);
                } else {
                    #pragma unroll
                    for (int e = 0; e < 4; ++e)
                        xseq[(sq * 16 + jj4 * 4 + e) * 256 + sr] = o[e];
                }
            }
            __syncthreads();
        }
    }

    // ============ stage Whh A-frags (split bf16) into WA ============
    // tile tt=(gi,u): rows = units gi*64 + u*16 + r ; A lane(g,r) elem j -> k = kc*32+8g+j
    for (int i = tid; i < 4096; i += NTHREADS) {
        int ln = i & 63, rest = i >> 6;
        int which = rest & 3, tt = rest >> 2;
        int kc = which & 1, lo = which >> 1;
        int gi = tt >> 2, u = tt & 3;
        int r = ln & 15, g = ln >> 4;
        const float* src = Whh + (gi * 64 + u * 16 + r) * 64 + kc * 32 + g * 8;
        union { bf16x8 v; unsigned short s[8]; } f;
        #pragma unroll
        for (int j = 0; j < 8; ++j) {
            float w = src[j];
            unsigned short h = f2bf(w);
            f.s[j] = lo ? (unsigned short)f2bf(w - bfh(h)) : h;
        }
        WA[(tt * 5 + lo * 2 + kc) * 64 + ln] = f.v;
    }
    // ext frag (k0..4 = wih_hi, wih_hi, wih_lo, gb_hi, gb_lo on g==0 lanes)
    for (int i = tid; i < 1024; i += NTHREADS) {
        int ln = i & 63, tt = i >> 6;
        int r = ln & 15, g = ln >> 4;
        union { bf16x8 v; unsigned u[4]; } f;
        f.u[0] = f.u[1] = f.u[2] = f.u[3] = 0u;
        if (g == 0) {
            int G = (tt >> 2) * 64 + (tt & 3) * 16 + r;
            float wih = Wih[G];
            float gb  = Bih[G] + Bhh[G];
            unsigned short wh = f2bf(wih);
            unsigned short wl = f2bf(wih - bfh(wh));
            unsigned short gh = f2bf(gb);
            unsigned short gl = f2bf(gb - bfh(gh));
            f.u[0] = (unsigned)wh | ((unsigned)wh << 16);
            f.u[1] = (unsigned)wl | ((unsigned)gh << 16);
            f.u[2] = (unsigned)gl;
        }
        WA[(tt * 5 + 4) * 64 + ln] = f.v;
    }
    __syncthreads();

    // ===================== recurrence =====================
    const int lane = tid & 63;
    const int wv   = tid >> 6;       // wave -> rows wv*16..+15
    const int g_   = lane >> 4;      // 0..3
    const int n    = lane & 15;      // batchrow within wave
    const bool glow  = (g_ < 2);
    const bool geven = ((g_ & 1) == 0);

    const float* xcol = xseq + wv * 16 + n;
    const u16x8* m0v = (const u16x8*)(smem + OFF_MOG);
    const u16x8* m2v = (const u16x8*)(smem + OFF_MOG + 128);
    const u16x8* m4v = (const u16x8*)(smem + OFF_MOG + 256);
    const uint4* m1p = (const uint4*)(smem + OFF_MOG + 384);
    const uint4* m3p = (const uint4*)(smem + OFF_MOG + 640);
    const float m0b_s = M0b[0], m2b_s = M2b[0], m4b_s = M4b[0];

    // hB[kc*8+j] = h[unit kc*32 + 8g_ + j] (fp32, B-operand order)
    float hB[16], cst[16];
    #pragma unroll
    for (int i = 0; i < 16; ++i) { hB[i] = 0.0f; cst[i] = 0.0f; }

#define MOG_DOT(TAB, BIAS)                                                    \
    {                                                                         \
        u16x8 w0 = (TAB)[g_], w1 = (TAB)[4 + g_];                             \
        float p = 0.0f;                                                       \
        _Pragma("unroll")                                                     \
        for (int j = 0; j < 8; ++j) {                                         \
            p += bfh((unsigned short)w0[j]) * hB[j];                          \
            p += bfh((unsigned short)w1[j]) * hB[8 + j];                      \
        }                                                                     \
        p += __shfl_xor(p, 16);                                               \
        p += __shfl_xor(p, 32);                                               \
        xt *= 2.0f * sigmoidf_(p + (BIAS));                                   \
    }

#define MOG_SCALE(TABP)                                                       \
    {                                                                         \
        _Pragma("unroll")                                                     \
        for (int kc = 0; kc < 2; ++kc) {                                      \
            _Pragma("unroll")                                                 \
            for (int q = 0; q < 2; ++q) {                                     \
                uint4 w4 = (TABP)[kc * 8 + 2 * g_ + q];                       \
                _Pragma("unroll")                                             \
                for (int i = 0; i < 4; ++i) {                                 \
                    unsigned pk = (&w4.x)[i];                                 \
                    float ww = __uint_as_float(pk << 16);                     \
                    float bb = __uint_as_float(pk & 0xffff0000u);             \
                    hB[kc * 8 + q * 4 + i] *= 2.0f * sigmoidf_(xt * ww + bb); \
                }                                                             \
            }                                                                 \
        }                                                                     \
    }

    #pragma unroll 1
    for (int t = 0; t < TSTEPS; ++t) {
        float xt = xcol[t * 256];

        // ---- mogrifier (fp32, lane-local xt) ----
        MOG_DOT(m0v, m0b_s)
        MOG_SCALE(m1p)
        MOG_DOT(m2v, m2b_s)
        MOG_SCALE(m3p)
        MOG_DOT(m4v, m4b_s)

        // ---- B-frags: h -> split bf16 ----
        union { bf16x8 v; unsigned u[4]; } bhi0, bhi1, blo0, blo1, bext;
        #pragma unroll
        for (int kc = 0; kc < 2; ++kc) {
            #pragma unroll
            for (int jp = 0; jp < 4; ++jp) {
                float a = hB[kc * 8 + 2 * jp], b = hB[kc * 8 + 2 * jp + 1];
                unsigned hi = cvt_pk_bf16(a, b);
                float ah = __uint_as_float(hi << 16);
                float bh = __uint_as_float(hi & 0xffff0000u);
                unsigned lo = cvt_pk_bf16(a - ah, b - bh);
                if (kc == 0) { bhi0.u[jp] = hi; blo0.u[jp] = lo; }
                else         { bhi1.u[jp] = hi; blo1.u[jp] = lo; }
            }
        }
        // ext B: j = {xt_hi, xt_lo, xt_hi, 1, 1, 0,0,0} (only k<8 used; A zero elsewhere)
        {
            unsigned xp = cvt_pk_bf16(xt, xt);
            unsigned xh = xp & 0xffffu;
            float xl = xt - __uint_as_float(xh << 16);
            unsigned xlp = cvt_pk_bf16(xl, xl);
            bext.u[0] = xh | (xlp << 16);
            bext.u[1] = xh | (0x3F80u << 16);
            bext.u[2] = 0x3F80u;
            bext.u[3] = 0u;
        }

        // ---- gates = Whh @ h + xt*Wih + b  (per-tile 7 MFMAs) ----
        f32x4 acc[16];
        #pragma unroll
        for (int tt = 0; tt < 16; ++tt) {
            const bf16x8 whi0 = WA[(tt * 5 + 0) * 64 + lane];
            const bf16x8 whi1 = WA[(tt * 5 + 1) * 64 + lane];
            const bf16x8 wlo0 = WA[(tt * 5 + 2) * 64 + lane];
            const bf16x8 wlo1 = WA[(tt * 5 + 3) * 64 + lane];
            const bf16x8 wext = WA[(tt * 5 + 4) * 64 + lane];
            f32x4 d = {0.0f, 0.0f, 0.0f, 0.0f};
            d = __builtin_amdgcn_mfma_f32_16x16x32_bf16(wext, bext.v, d, 0, 0, 0);
            d = __builtin_amdgcn_mfma_f32_16x16x32_bf16(whi0, bhi0.v, d, 0, 0, 0);
            d = __builtin_amdgcn_mfma_f32_16x16x32_bf16(whi1, bhi1.v, d, 0, 0, 0);
            d = __builtin_amdgcn_mfma_f32_16x16x32_bf16(whi0, blo0.v, d, 0, 0, 0);
            d = __builtin_amdgcn_mfma_f32_16x16x32_bf16(whi1, blo1.v, d, 0, 0, 0);
            d = __builtin_amdgcn_mfma_f32_16x16x32_bf16(wlo0, bhi0.v, d, 0, 0, 0);
            d = __builtin_amdgcn_mfma_f32_16x16x32_bf16(wlo1, bhi1.v, d, 0, 0, 0);
            acc[tt] = d;
        }

        // ---- activations: lane(g_,n) owns units 16u+4g_+e of batchrow n ----
        float hn[4][4];
        #pragma unroll
        for (int u = 0; u < 4; ++u) {
            f32x4 iv = acc[0 * 4 + u], fv = acc[1 * 4 + u];
            f32x4 gv = acc[2 * 4 + u], ov = acc[3 * 4 + u];
            #pragma unroll
            for (int e = 0; e < 4; ++e) {
                float cc = sigmoidf_(fv[e]) * cst[u * 4 + e] + sigmoidf_(iv[e]) * tanhf_(gv[e]);
                cst[u * 4 + e] = cc;
                hn[u][e] = sigmoidf_(ov[e]) * tanhf_(cc);
            }
        }

        // ---- redistribute hn (unit 16u+4g+e) -> hB (unit kc*32+8g+j), 4-lane xor shuffles ----
        // stage 1 (xor 32): g<2 sends odd-u slots, g>=2 sends even-u slots
        #pragma unroll
        for (int up = 0; up < 2; ++up) {
            #pragma unroll
            for (int e = 0; e < 4; ++e) {
                float send = glow ? hn[2 * up + 1][e] : hn[2 * up][e];
                float got = __shfl_xor(send, 32);
                hn[2 * up + 1][e] = glow ? got : hn[2 * up + 1][e];
                hn[2 * up][e]     = glow ? hn[2 * up][e] : got;
            }
        }
        // stage 2 (xor 16): g even sends odd-u slots, g odd sends even-u slots
        #pragma unroll
        for (int up = 0; up < 2; ++up) {
            #pragma unroll
            for (int e = 0; e < 4; ++e) {
                float send = geven ? hn[2 * up + 1][e] : hn[2 * up][e];
                float got = __shfl_xor(send, 16);
                hn[2 * up + 1][e] = geven ? got : hn[2 * up + 1][e];
                hn[2 * up][e]     = geven ? hn[2 * up][e] : got;
            }
        }
        // final: hB[kc*8+j] = hn[2kc + (j>>2)][j&3]
        #pragma unroll
        for (int kc = 0; kc < 2; ++kc)
            #pragma unroll
            for (int j = 0; j < 8; ++j)
                hB[kc * 8 + j] = hn[2 * kc + (j >> 2)][j & 3];
    }

    // ===================== projection =====================
    const float4* wp4 = (const float4*)(smem + OFF_MOG + 896);
    #pragma unroll
    for (int p = 0; p < 5; ++p) {
        float ap = 0.0f;
        #pragma unroll
        for (int kc = 0; kc < 2; ++kc) {
            #pragma unroll
            for (int q = 0; q < 2; ++q) {
                float4 w = wp4[p * 16 + kc * 8 + 2 * g_ + q];
                ap += w.x * hB[kc * 8 + q * 4 + 0] + w.y * hB[kc * 8 + q * 4 + 1]
                    + w.z * hB[kc * 8 + q * 4 + 2] + w.w * hB[kc * 8 + q * 4 + 3];
            }
        }
        ap += __shfl_xor(ap, 16);
        ap += __shfl_xor(ap, 32);
        if (g_ == 0)
            out[(rowbase + wv * 16 + n) * 5 + p] = ap + Bp[p];
    }
}

extern "C" void kernel_launch(void* const* d_in, const int* in_sizes, int n_in,
                              void* d_out, int out_size, void* d_ws, size_t ws_size,
                              hipStream_t stream) {
    const float* x   = (const float*)d_in[0];
    const float* W1  = (const float*)d_in[1];
    const float* B1  = (const float*)d_in[2];
    const float* W2  = (const float*)d_in[3];
    const float* B2  = (const float*)d_in[4];
    const float* W3  = (const float*)d_in[5];
    const float* B3  = (const float*)d_in[6];
    const float* W4  = (const float*)d_in[7];
    const float* B4  = (const float*)d_in[8];
    const float* M0w = (const float*)d_in[9];
    const float* M0b = (const float*)d_in[10];
    const float* M1w = (const float*)d_in[11];
    const float* M1b = (const float*)d_in[12];
    const float* M2w = (const float*)d_in[13];
    const float* M2b = (const float*)d_in[14];
    const float* M3w = (const float*)d_in[15];
    const float* M3b = (const float*)d_in[16];
    const float* M4w = (const float*)d_in[17];
    const float* M4b = (const float*)d_in[18];
    const float* Wih = (const float*)d_in[19];
    const float* Bih = (const float*)d_in[20];
    const float* Whh = (const float*)d_in[21];
    const float* Bhh = (const float*)d_in[22];
    const float* Wp  = (const float*)d_in[23];
    const float* Bp  = (const float*)d_in[24];

    int B = in_sizes[0] / HID;          // 262144
    int nblocks = B / ROWS_PB;          // 1024

    hipLaunchKernelGGL(moglstm_mfma2, dim3(nblocks), dim3(NTHREADS), 0, stream,
                       x, W1, B1, W2, B2, W3, B3, W4, B4,
                       M0w, M0b, M1w, M1b, M2w, M2b, M3w, M3b, M4w, M4b,
                       Wih, Bih, Whh, Bhh, Wp, Bp, (float*)d_out);
}

// Round 4
// 5605.850 us; speedup vs baseline: 2.0733x; 2.0733x over previous
//
#include <hip/hip_runtime.h>

#define HID 64
#define TSTEPS 64
#define NTHREADS 512
#define ROWS_PB 128

typedef __attribute__((ext_vector_type(8))) short bf16x8;
typedef __attribute__((ext_vector_type(4))) float f32x4;

__device__ __forceinline__ float fast_exp2(float x) { return __builtin_amdgcn_exp2f(x); }
__device__ __forceinline__ float fast_rcp(float x)  { return __builtin_amdgcn_rcpf(x); }
#define LOG2E 1.44269504088896341f
__device__ __forceinline__ float sigmoidf_(float x) { return fast_rcp(1.0f + fast_exp2(-LOG2E * x)); }
__device__ __forceinline__ float tanhf_(float x)    { return 1.0f - 2.0f * fast_rcp(1.0f + fast_exp2(2.0f * LOG2E * x)); }

__device__ __forceinline__ unsigned short f2bf(float f) {   // RNE fp32->bf16
    unsigned u = __float_as_uint(f);
    u = u + 0x7fffu + ((u >> 16) & 1u);
    return (unsigned short)(u >> 16);
}
__device__ __forceinline__ float bfh(unsigned short h) { return __uint_as_float(((unsigned)h) << 16); }
__device__ __forceinline__ unsigned cvt_pk_bf16(float a, float b) {  // low16=bf(a), high16=bf(b)
    unsigned r;
    asm("v_cvt_pk_bf16_f32 %0, %1, %2" : "=v"(r) : "v"(a), "v"(b));
    return r;
}

// ---------------- LDS layout (bytes) ----------------
// [0,     65536)  WA   : 16 tiles x 4 frags (hi-kc0, hi-kc1, lo-kc0, lo-kc1) x 64 lanes x 16B
// [65536, 69632)  EXT  : 16 tiles x 16 rows x 16B   (bias+Wih frag, g==0 lanes only)
// [69632, 69648)  ZERO : 16B zeros (broadcast source for g>0 lanes)
// [69648, 72740)  MOG  : fp32 tables (offsets in floats below)
// stem overlay: ping [0,34816), pong [34816,69632) -- both freed before WA staging
#define OFF_WA    0
#define OFF_EXT   65536
#define OFF_ZERO  69632
#define OFF_MOGB  69648
#define SMEM_TOTAL 72752

#define M0W 0
#define M2W 64
#define M4W 128
#define M1W 192
#define M1B 256
#define M3W 320
#define M3B 384
#define WPo 448
#define BPo 768

__global__ __launch_bounds__(NTHREADS, 4) void moglstm_mfma3(
    const float* __restrict__ x,
    const float* __restrict__ W1, const float* __restrict__ B1,
    const float* __restrict__ W2, const float* __restrict__ B2,
    const float* __restrict__ W3, const float* __restrict__ B3,
    const float* __restrict__ W4, const float* __restrict__ B4,
    const float* __restrict__ M0w, const float* __restrict__ M0b,
    const float* __restrict__ M1w, const float* __restrict__ M1b,
    const float* __restrict__ M2w, const float* __restrict__ M2b,
    const float* __restrict__ M3w, const float* __restrict__ M3b,
    const float* __restrict__ M4w, const float* __restrict__ M4b,
    const float* __restrict__ Wih, const float* __restrict__ Bih,
    const float* __restrict__ Whh, const float* __restrict__ Bhh,
    const float* __restrict__ Wp,  const float* __restrict__ Bp,
    float* __restrict__ out)
{
    __shared__ __align__(16) char smem[SMEM_TOTAL];
    bf16x8* WA   = (bf16x8*)(smem + OFF_WA);
    float*  mogf = (float*)(smem + OFF_MOGB);
    float*  ping = (float*)(smem);
    float*  pong = (float*)(smem + 34816);

    const int tid = threadIdx.x;
    const long rowbase = (long)blockIdx.x * ROWS_PB;

    // ---- stage mog/proj tables (region disjoint from stem overlay) ----
    if (tid < 64) {
        mogf[M0W + tid] = M0w[tid];
        mogf[M2W + tid] = M2w[tid];
        mogf[M4W + tid] = M4w[tid];
        mogf[M1W + tid] = M1w[tid];
        mogf[M1B + tid] = M1b[tid];
        mogf[M3W + tid] = M3w[tid];
        mogf[M3B + tid] = M3b[tid];
    }
    for (int i = tid; i < 320; i += NTHREADS) mogf[WPo + i] = Wp[i];
    if (tid < 5) mogf[BPo + tid] = Bp[tid];

    // ================= MLP stem (4x Linear(64->64)+ReLU) =================
    for (int i = tid; i < ROWS_PB * 16; i += NTHREADS) {
        int r = i >> 4, c4 = i & 15;
        *(float4*)&ping[r * 68 + c4 * 4] = ((const float4*)x)[(rowbase + r) * 16 + c4];
    }
    __syncthreads();
    {
        const int sr = tid & 127;   // row
        const int sq = tid >> 7;    // quarter (wave-uniform) -> units sq*16..+15
        const float* Ws[4] = {W1, W2, W3, W4};
        const float* Bs[4] = {B1, B2, B3, B4};
        float rin[HID];
        #pragma unroll
        for (int L = 0; L < 4; ++L) {
            const float* SRC = (L & 1) ? pong : ping;
            float* DST       = (L & 1) ? ping : pong;
            #pragma unroll
            for (int k4 = 0; k4 < 16; ++k4) {
                float4 v = *(const float4*)&SRC[sr * 68 + k4 * 4];
                rin[4*k4+0] = v.x; rin[4*k4+1] = v.y; rin[4*k4+2] = v.z; rin[4*k4+3] = v.w;
            }
            __syncthreads();
            const float* W = Ws[L];
            const float* Bb = Bs[L];
            #pragma unroll
            for (int jj4 = 0; jj4 < 4; ++jj4) {
                float o[4];
                #pragma unroll
                for (int e = 0; e < 4; ++e) {
                    int j = sq * 16 + jj4 * 4 + e;
                    float a = Bb[j];
                    const float4* wr = (const float4*)(W + j * 64);  // wave-uniform -> s_load
                    #pragma unroll
                    for (int k4 = 0; k4 < 16; ++k4) {
                        float4 w = wr[k4];
                        a += w.x*rin[4*k4] + w.y*rin[4*k4+1] + w.z*rin[4*k4+2] + w.w*rin[4*k4+3];
                    }
                    o[e] = fmaxf(a, 0.0f);
                }
                *(float4*)&DST[sr * 68 + sq * 16 + jj4 * 4] = make_float4(o[0], o[1], o[2], o[3]);
            }
            __syncthreads();
        }
    }
    // final stem output is in ping (L4 wrote pong->ping)

    // ---- each thread pulls its own row's sequence into private scratch ----
    const int lane = tid & 63;
    const int wv   = tid >> 6;       // wave -> rows wv*16..+15
    const int g_   = lane >> 4;      // 0..3
    const int n    = lane & 15;      // batchrow within wave (and A-row / D-col)
    const int myrow = wv * 16 + n;

    float xseq[TSTEPS];              // dynamic-indexed -> scratch (coalesced)
    #pragma unroll
    for (int t4 = 0; t4 < 16; ++t4)
        *(float4*)&xseq[t4 * 4] = *(const float4*)&ping[myrow * 68 + t4 * 4];
    __syncthreads();   // stem buffers dead; safe to overwrite with WA

    // ============ stage Whh split-bf16 A-frags (frag order) ============
    // tile tt=(gi,u): rows = units gi*64 + u*16 + r ; lane(g,r) elem j -> k = kc*32+8g+j
    for (int i = tid; i < 4096; i += NTHREADS) {
        int ln = i & 63, rest = i >> 6;
        int which = rest & 3, tt = rest >> 2;
        int kc = which & 1, lo = which >> 1;
        int gi = tt >> 2, u = tt & 3;
        int r = ln & 15, g = ln >> 4;
        const float* src = Whh + (gi * 64 + u * 16 + r) * 64 + kc * 32 + g * 8;
        union { bf16x8 v; unsigned short s[8]; } f;
        #pragma unroll
        for (int j = 0; j < 8; ++j) {
            float w = src[j];
            unsigned short h = f2bf(w);
            f.s[j] = lo ? (unsigned short)f2bf(w - bfh(h)) : h;
        }
        WA[(tt * 4 + lo * 2 + kc) * 64 + ln] = f.v;
    }
    // compact ext frag: A[u=r][k0..4] = {wih_hi, wih_hi, wih_lo, gb_hi, gb_lo}
    if (tid < 256) {
        int tt = tid >> 4, r = tid & 15;
        int G = (tt >> 2) * 64 + (tt & 3) * 16 + r;
        float wih = Wih[G];
        float gb  = Bih[G] + Bhh[G];
        unsigned short wh = f2bf(wih);
        unsigned short wl = f2bf(wih - bfh(wh));
        unsigned short gh = f2bf(gb);
        unsigned short gl = f2bf(gb - bfh(gh));
        union { bf16x8 v; unsigned u[4]; } f;
        f.u[0] = (unsigned)wh | ((unsigned)wh << 16);
        f.u[1] = (unsigned)wl | ((unsigned)gh << 16);
        f.u[2] = (unsigned)gl;
        f.u[3] = 0u;
        *(bf16x8*)(smem + OFF_EXT + tt * 256 + r * 16) = f.v;
    } else if (tid < 260) {
        ((float*)(smem + OFF_ZERO))[tid - 256] = 0.0f;
    }
    __syncthreads();

    // ===================== mogrifier-LSTM recurrence =====================
    const char* extb   = smem + ((g_ == 0) ? (OFF_EXT + n * 16) : OFF_ZERO);
    const int   extstep = (g_ == 0) ? 256 : 0;
    const float m0b_s = M0b[0], m2b_s = M2b[0], m4b_s = M4b[0];
    const bool glow  = (g_ < 2);
    const bool geven = ((g_ & 1) == 0);

    // hB[kc*8+j] = h[unit kc*32 + 8g_ + j] of row n (fp32, B-operand order)
    float hB[16];
    f32x4 cst[4];
    #pragma unroll
    for (int i = 0; i < 16; ++i) hB[i] = 0.0f;
    #pragma unroll
    for (int u = 0; u < 4; ++u) cst[u] = (f32x4){0.0f, 0.0f, 0.0f, 0.0f};

    float xt_cur = xseq[0];

#define MOG_DOT(MOFF, BIAS)                                                   \
    {                                                                         \
        float4 w0 = *(const float4*)&mogf[(MOFF) + g_ * 8];                   \
        float4 w1 = *(const float4*)&mogf[(MOFF) + g_ * 8 + 4];               \
        float4 w2 = *(const float4*)&mogf[(MOFF) + 32 + g_ * 8];              \
        float4 w3 = *(const float4*)&mogf[(MOFF) + 32 + g_ * 8 + 4];          \
        float p = w0.x*hB[0] + w0.y*hB[1] + w0.z*hB[2] + w0.w*hB[3]           \
                + w1.x*hB[4] + w1.y*hB[5] + w1.z*hB[6] + w1.w*hB[7]           \
                + w2.x*hB[8] + w2.y*hB[9] + w2.z*hB[10] + w2.w*hB[11]         \
                + w3.x*hB[12] + w3.y*hB[13] + w3.z*hB[14] + w3.w*hB[15];      \
        p += __shfl_xor(p, 16);                                               \
        p += __shfl_xor(p, 32);                                               \
        xt *= 2.0f * sigmoidf_(p + (BIAS));                                   \
    }

#define MOG_SCALE(WOFF, BOFF)                                                 \
    {                                                                         \
        _Pragma("unroll")                                                     \
        for (int kc = 0; kc < 2; ++kc) {                                      \
            _Pragma("unroll")                                                 \
            for (int q = 0; q < 2; ++q) {                                     \
                float4 w4 = *(const float4*)&mogf[(WOFF) + kc*32 + g_*8 + q*4]; \
                float4 b4 = *(const float4*)&mogf[(BOFF) + kc*32 + g_*8 + q*4]; \
                int bse = kc * 8 + q * 4;                                     \
                hB[bse+0] *= 2.0f * sigmoidf_(xt * w4.x + b4.x);              \
                hB[bse+1] *= 2.0f * sigmoidf_(xt * w4.y + b4.y);              \
                hB[bse+2] *= 2.0f * sigmoidf_(xt * w4.z + b4.z);              \
                hB[bse+3] *= 2.0f * sigmoidf_(xt * w4.w + b4.w);              \
            }                                                                 \
        }                                                                     \
    }

    #pragma unroll 1
    for (int t = 0; t < TSTEPS; ++t) {
        float xn = xseq[(t + 1) & 63];   // prefetch next xt (scratch load)
        float xt = xt_cur;

        // ---- mogrifier (fp32) ----
        MOG_DOT(M0W, m0b_s)
        MOG_SCALE(M1W, M1B)
        MOG_DOT(M2W, m2b_s)
        MOG_SCALE(M3W, M3B)
        MOG_DOT(M4W, m4b_s)

        // ---- B-frags: h -> split bf16 ----
        union { bf16x8 v; unsigned u[4]; } bhi0, bhi1, blo0, blo1, bext;
        #pragma unroll
        for (int kc = 0; kc < 2; ++kc) {
            #pragma unroll
            for (int jp = 0; jp < 4; ++jp) {
                float a = hB[kc * 8 + 2 * jp], b = hB[kc * 8 + 2 * jp + 1];
                unsigned hi = cvt_pk_bf16(a, b);
                float ah = __uint_as_float(hi << 16);
                float bh = __uint_as_float(hi & 0xffff0000u);
                unsigned lo = cvt_pk_bf16(a - ah, b - bh);
                if (kc == 0) { bhi0.u[jp] = hi; blo0.u[jp] = lo; }
                else         { bhi1.u[jp] = hi; blo1.u[jp] = lo; }
            }
        }
        {   // ext B: j = {xt_hi, xt_lo, xt_hi, 1, 1, 0, 0, 0}
            unsigned xh = cvt_pk_bf16(xt, xt) & 0xffffu;
            float xl = xt - bfh((unsigned short)xh);
            unsigned xlp = cvt_pk_bf16(xl, xl) & 0xffffu;
            bext.u[0] = xh | (xlp << 16);
            bext.u[1] = xh | (0x3F80u << 16);
            bext.u[2] = 0x3F80u;
            bext.u[3] = 0u;
        }

        auto gate_tile = [&](int tt) -> f32x4 {
            bf16x8 whi0 = WA[(tt * 4 + 0) * 64 + lane];
            bf16x8 whi1 = WA[(tt * 4 + 1) * 64 + lane];
            bf16x8 wlo0 = WA[(tt * 4 + 2) * 64 + lane];
            bf16x8 wlo1 = WA[(tt * 4 + 3) * 64 + lane];
            bf16x8 wext = *(const bf16x8*)(extb + tt * extstep);
            f32x4 d = {0.0f, 0.0f, 0.0f, 0.0f};
            d = __builtin_amdgcn_mfma_f32_16x16x32_bf16(wext, bext.v, d, 0, 0, 0);
            d = __builtin_amdgcn_mfma_f32_16x16x32_bf16(whi0, bhi0.v, d, 0, 0, 0);
            d = __builtin_amdgcn_mfma_f32_16x16x32_bf16(whi1, bhi1.v, d, 0, 0, 0);
            d = __builtin_amdgcn_mfma_f32_16x16x32_bf16(whi0, blo0.v, d, 0, 0, 0);
            d = __builtin_amdgcn_mfma_f32_16x16x32_bf16(whi1, blo1.v, d, 0, 0, 0);
            d = __builtin_amdgcn_mfma_f32_16x16x32_bf16(wlo0, bhi0.v, d, 0, 0, 0);
            d = __builtin_amdgcn_mfma_f32_16x16x32_bf16(wlo1, bhi1.v, d, 0, 0, 0);
            return d;
        };

        // ---- half 1: gates i (tiles 0-3) and g (tiles 8-11) -> p1 ----
        f32x4 p1[4];
        {
            f32x4 acci[4], accg[4];
            #pragma unroll
            for (int u = 0; u < 4; ++u) { acci[u] = gate_tile(u); accg[u] = gate_tile(8 + u); }
            #pragma unroll
            for (int u = 0; u < 4; ++u)
                #pragma unroll
                for (int e = 0; e < 4; ++e)
                    p1[u][e] = sigmoidf_(acci[u][e]) * tanhf_(accg[u][e]);
        }

        // ---- half 2: gates f (tiles 4-7) and o (tiles 12-15) -> c, h ----
        float hn[4][4];
        {
            f32x4 accf[4], acco[4];
            #pragma unroll
            for (int u = 0; u < 4; ++u) { accf[u] = gate_tile(4 + u); acco[u] = gate_tile(12 + u); }
            #pragma unroll
            for (int u = 0; u < 4; ++u)
                #pragma unroll
                for (int e = 0; e < 4; ++e) {
                    float cc = sigmoidf_(accf[u][e]) * cst[u][e] + p1[u][e];
                    cst[u][e] = cc;
                    hn[u][e] = sigmoidf_(acco[u][e]) * tanhf_(cc);
                }
        }

        // ---- redistribute hn (unit 16u+4g+e, row n) -> hB (unit kc*32+8g+j) ----
        #pragma unroll
        for (int up = 0; up < 2; ++up) {
            #pragma unroll
            for (int e = 0; e < 4; ++e) {
                float send = glow ? hn[2 * up + 1][e] : hn[2 * up][e];
                float got = __shfl_xor(send, 32);
                hn[2 * up + 1][e] = glow ? got : hn[2 * up + 1][e];
                hn[2 * up][e]     = glow ? hn[2 * up][e] : got;
            }
        }
        #pragma unroll
        for (int up = 0; up < 2; ++up) {
            #pragma unroll
            for (int e = 0; e < 4; ++e) {
                float send = geven ? hn[2 * up + 1][e] : hn[2 * up][e];
                float got = __shfl_xor(send, 16);
                hn[2 * up + 1][e] = geven ? got : hn[2 * up + 1][e];
                hn[2 * up][e]     = geven ? hn[2 * up][e] : got;
            }
        }
        #pragma unroll
        for (int kc = 0; kc < 2; ++kc)
            #pragma unroll
            for (int j = 0; j < 8; ++j)
                hB[kc * 8 + j] = hn[2 * kc + (j >> 2)][j & 3];

        xt_cur = xn;
    }

    // ===================== projection: out = h @ Wp^T + Bp =====================
    #pragma unroll
    for (int p = 0; p < 5; ++p) {
        float ap = 0.0f;
        #pragma unroll
        for (int kc = 0; kc < 2; ++kc) {
            #pragma unroll
            for (int q = 0; q < 2; ++q) {
                float4 w = *(const float4*)&mogf[WPo + p * 64 + kc * 32 + g_ * 8 + q * 4];
                ap += w.x * hB[kc * 8 + q * 4 + 0] + w.y * hB[kc * 8 + q * 4 + 1]
                    + w.z * hB[kc * 8 + q * 4 + 2] + w.w * hB[kc * 8 + q * 4 + 3];
            }
        }
        ap += __shfl_xor(ap, 16);
        ap += __shfl_xor(ap, 32);
        if (g_ == 0)
            out[(rowbase + myrow) * 5 + p] = ap + mogf[BPo + p];
    }
}

extern "C" void kernel_launch(void* const* d_in, const int* in_sizes, int n_in,
                              void* d_out, int out_size, void* d_ws, size_t ws_size,
                              hipStream_t stream) {
    const float* x   = (const float*)d_in[0];
    const float* W1  = (const float*)d_in[1];
    const float* B1  = (const float*)d_in[2];
    const float* W2  = (const float*)d_in[3];
    const float* B2  = (const float*)d_in[4];
    const float* W3  = (const float*)d_in[5];
    const float* B3  = (const float*)d_in[6];
    const float* W4  = (const float*)d_in[7];
    const float* B4  = (const float*)d_in[8];
    const float* M0w = (const float*)d_in[9];
    const float* M0b = (const float*)d_in[10];
    const float* M1w = (const float*)d_in[11];
    const float* M1b = (const float*)d_in[12];
    const float* M2w = (const float*)d_in[13];
    const float* M2b = (const float*)d_in[14];
    const float* M3w = (const float*)d_in[15];
    const float* M3b = (const float*)d_in[16];
    const float* M4w = (const float*)d_in[17];
    const float* M4b = (const float*)d_in[18];
    const float* Wih = (const float*)d_in[19];
    const float* Bih = (const float*)d_in[20];
    const float* Whh = (const float*)d_in[21];
    const float* Bhh = (const float*)d_in[22];
    const float* Wp  = (const float*)d_in[23];
    const float* Bp  = (const float*)d_in[24];

    int B = in_sizes[0] / HID;          // 262144
    int nblocks = B / ROWS_PB;          // 2048

    hipLaunchKernelGGL(moglstm_mfma3, dim3(nblocks), dim3(NTHREADS), 0, stream,
                       x, W1, B1, W2, B2, W3, B3, W4, B4,
                       M0w, M0b, M1w, M1b, M2w, M2b, M3w, M3b, M4w, M4b,
                       Wih, Bih, Whh, Bhh, Wp, Bp, (float*)d_out);
}

// Round 5
// 3280.693 us; speedup vs baseline: 3.5426x; 1.7087x over previous
//
#include <hip/hip_runtime.h>

#define HID 64
#define TSTEPS 64
#define NTHREADS 512
#define ROWS_PB 128

typedef __attribute__((ext_vector_type(8))) short bf16x8;
typedef __attribute__((ext_vector_type(4))) float f32x4;

__device__ __forceinline__ float fast_exp2(float x) { return __builtin_amdgcn_exp2f(x); }
__device__ __forceinline__ float fast_rcp(float x)  { return __builtin_amdgcn_rcpf(x); }
#define LOG2E 1.44269504088896341f
__device__ __forceinline__ float sigmoidf_(float x) { return fast_rcp(1.0f + fast_exp2(-LOG2E * x)); }
__device__ __forceinline__ float tanhf_(float x)    { return 1.0f - 2.0f * fast_rcp(1.0f + fast_exp2(2.0f * LOG2E * x)); }

__device__ __forceinline__ unsigned short f2bf(float f) {   // RNE fp32->bf16
    unsigned u = __float_as_uint(f);
    u = u + 0x7fffu + ((u >> 16) & 1u);
    return (unsigned short)(u >> 16);
}
__device__ __forceinline__ float bfh(unsigned short h) { return __uint_as_float(((unsigned)h) << 16); }
__device__ __forceinline__ unsigned cvt_pk_bf16(float a, float b) {  // low16=bf(a), high16=bf(b)
    unsigned r;
    asm("v_cvt_pk_bf16_f32 %0, %1, %2" : "=v"(r) : "v"(a), "v"(b));
    return r;
}

// ---------------- LDS layout (bytes) ----------------
// [0,     65536)  WA   : 16 tiles x 4 frags (hi-kc0, hi-kc1, lo-kc0, lo-kc1) x 64 lanes x 16B
// [65536, 69632)  EXT  : 16 tiles x 16 rows x 16B   (bias+Wih frag, g==0 lanes only)
// [69632, 69648)  ZERO : 16B zeros (broadcast source for g>0 lanes)
// [69648, 72740)  MOG  : fp32 tables (offsets in floats below)
// [73728,106496)  XSEQ : [t=64][row=128] f32
// stem overlay: ping [0,34816), pong [34816,69632) -- freed before WA/EXT staging
#define OFF_WA    0
#define OFF_EXT   65536
#define OFF_ZERO  69632
#define OFF_MOGB  69648
#define OFF_XSEQ  73728
#define SMEM_TOTAL 106496

#define M0W 0
#define M2W 64
#define M4W 128
#define M1W 192
#define M1B 256
#define M3W 320
#define M3B 384
#define WPo 448
#define BPo 768

__global__ __launch_bounds__(NTHREADS, 2) void moglstm_mfma4(
    const float* __restrict__ x,
    const float* __restrict__ W1, const float* __restrict__ B1,
    const float* __restrict__ W2, const float* __restrict__ B2,
    const float* __restrict__ W3, const float* __restrict__ B3,
    const float* __restrict__ W4, const float* __restrict__ B4,
    const float* __restrict__ M0w, const float* __restrict__ M0b,
    const float* __restrict__ M1w, const float* __restrict__ M1b,
    const float* __restrict__ M2w, const float* __restrict__ M2b,
    const float* __restrict__ M3w, const float* __restrict__ M3b,
    const float* __restrict__ M4w, const float* __restrict__ M4b,
    const float* __restrict__ Wih, const float* __restrict__ Bih,
    const float* __restrict__ Whh, const float* __restrict__ Bhh,
    const float* __restrict__ Wp,  const float* __restrict__ Bp,
    float* __restrict__ out)
{
    __shared__ __align__(16) char smem[SMEM_TOTAL];
    bf16x8* WA    = (bf16x8*)(smem + OFF_WA);
    float*  mogf  = (float*)(smem + OFF_MOGB);
    float*  sXseq = (float*)(smem + OFF_XSEQ);
    float*  ping  = (float*)(smem);
    float*  pong  = (float*)(smem + 34816);

    const int tid = threadIdx.x;
    const long rowbase = (long)blockIdx.x * ROWS_PB;

    // ---- stage mog/proj tables (region disjoint from stem overlay) ----
    if (tid < 64) {
        mogf[M0W + tid] = M0w[tid];
        mogf[M2W + tid] = M2w[tid];
        mogf[M4W + tid] = M4w[tid];
        mogf[M1W + tid] = M1w[tid];
        mogf[M1B + tid] = M1b[tid];
        mogf[M3W + tid] = M3w[tid];
        mogf[M3B + tid] = M3b[tid];
    }
    for (int i = tid; i < 320; i += NTHREADS) mogf[WPo + i] = Wp[i];
    if (tid < 5) mogf[BPo + tid] = Bp[tid];

    // ================= MLP stem (4x Linear(64->64)+ReLU) =================
    for (int i = tid; i < ROWS_PB * 16; i += NTHREADS) {
        int r = i >> 4, c4 = i & 15;
        *(float4*)&ping[r * 68 + c4 * 4] = ((const float4*)x)[(rowbase + r) * 16 + c4];
    }
    __syncthreads();
    {
        const int sr = tid & 127;   // row
        const int sq = tid >> 7;    // quarter (wave-uniform) -> units sq*16..+15
        const float* Ws[4] = {W1, W2, W3, W4};
        const float* Bs[4] = {B1, B2, B3, B4};
        float rin[HID];
        #pragma unroll
        for (int L = 0; L < 4; ++L) {
            const float* SRC = (L & 1) ? pong : ping;
            float* DST       = (L & 1) ? ping : pong;
            #pragma unroll
            for (int k4 = 0; k4 < 16; ++k4) {
                float4 v = *(const float4*)&SRC[sr * 68 + k4 * 4];
                rin[4*k4+0] = v.x; rin[4*k4+1] = v.y; rin[4*k4+2] = v.z; rin[4*k4+3] = v.w;
            }
            __syncthreads();
            const float* W = Ws[L];
            const float* Bb = Bs[L];
            #pragma unroll
            for (int jj4 = 0; jj4 < 4; ++jj4) {
                float o[4];
                #pragma unroll
                for (int e = 0; e < 4; ++e) {
                    int j = sq * 16 + jj4 * 4 + e;
                    float a = Bb[j];
                    const float4* wr = (const float4*)(W + j * 64);  // wave-uniform -> s_load
                    #pragma unroll
                    for (int k4 = 0; k4 < 16; ++k4) {
                        float4 w = wr[k4];
                        a += w.x*rin[4*k4] + w.y*rin[4*k4+1] + w.z*rin[4*k4+2] + w.w*rin[4*k4+3];
                    }
                    o[e] = fmaxf(a, 0.0f);
                }
                *(float4*)&DST[sr * 68 + sq * 16 + jj4 * 4] = make_float4(o[0], o[1], o[2], o[3]);
            }
            __syncthreads();
        }
    }
    // final stem output is in ping (L4 wrote pong->ping)

    // ---- transpose stem output into XSEQ[t][row] (disjoint region) ----
    for (int i = tid; i < TSTEPS * ROWS_PB; i += NTHREADS) {
        int t = i >> 7, r = i & 127;
        sXseq[i] = ping[r * 68 + t];
    }
    // ---- compact ext frag (pong region is dead now) ----
    if (tid < 256) {
        int tt = tid >> 4, r = tid & 15;
        int G = (tt >> 2) * 64 + (tt & 3) * 16 + r;
        float wih = Wih[G];
        float gb  = Bih[G] + Bhh[G];
        unsigned short wh = f2bf(wih);
        unsigned short wl = f2bf(wih - bfh(wh));
        unsigned short gh = f2bf(gb);
        unsigned short gl = f2bf(gb - bfh(gh));
        union { bf16x8 v; unsigned u[4]; } f;
        f.u[0] = (unsigned)wh | ((unsigned)wh << 16);
        f.u[1] = (unsigned)wl | ((unsigned)gh << 16);
        f.u[2] = (unsigned)gl;
        f.u[3] = 0u;
        *(bf16x8*)(smem + OFF_EXT + tt * 256 + r * 16) = f.v;
    } else if (tid < 260) {
        ((float*)(smem + OFF_ZERO))[tid - 256] = 0.0f;
    }
    __syncthreads();   // ping reads done; WA may overwrite it

    // ============ stage Whh split-bf16 A-frags (frag order) ============
    // tile tt=(gi,u): rows = units gi*64 + u*16 + r ; lane(g,r) elem j -> k = kc*32+8g+j
    for (int i = tid; i < 4096; i += NTHREADS) {
        int ln = i & 63, rest = i >> 6;
        int which = rest & 3, tt = rest >> 2;
        int kc = which & 1, lo = which >> 1;
        int gi = tt >> 2, u = tt & 3;
        int r = ln & 15, g = ln >> 4;
        const float* src = Whh + (gi * 64 + u * 16 + r) * 64 + kc * 32 + g * 8;
        union { bf16x8 v; unsigned short s[8]; } f;
        #pragma unroll
        for (int j = 0; j < 8; ++j) {
            float w = src[j];
            unsigned short h = f2bf(w);
            f.s[j] = lo ? (unsigned short)f2bf(w - bfh(h)) : h;
        }
        WA[(tt * 4 + lo * 2 + kc) * 64 + ln] = f.v;
    }
    __syncthreads();

    // ===================== mogrifier-LSTM recurrence =====================
    const int lane = tid & 63;
    const int wv   = tid >> 6;       // wave -> rows wv*16..+15
    const int g_   = lane >> 4;      // 0..3
    const int n    = lane & 15;      // batchrow within wave (A-row / D-col)
    const int myrow = wv * 16 + n;

    const char* extb    = smem + ((g_ == 0) ? (OFF_EXT + n * 16) : OFF_ZERO);
    const int   extstep = (g_ == 0) ? 256 : 0;
    const float m0b_s = M0b[0], m2b_s = M2b[0], m4b_s = M4b[0];
    const bool glow  = (g_ < 2);
    const bool geven = ((g_ & 1) == 0);

    // hB[kc*8+j] = h[unit kc*32 + 8g_ + j] of row n (fp32, B-operand order)
    float hB[16];
    f32x4 cst[4];
    #pragma unroll
    for (int i = 0; i < 16; ++i) hB[i] = 0.0f;
    #pragma unroll
    for (int u = 0; u < 4; ++u) cst[u] = (f32x4){0.0f, 0.0f, 0.0f, 0.0f};

#define MOG_DOT(MOFF, BIAS)                                                   \
    {                                                                         \
        float4 w0 = *(const float4*)&mogf[(MOFF) + g_ * 8];                   \
        float4 w1 = *(const float4*)&mogf[(MOFF) + g_ * 8 + 4];               \
        float4 w2 = *(const float4*)&mogf[(MOFF) + 32 + g_ * 8];              \
        float4 w3 = *(const float4*)&mogf[(MOFF) + 32 + g_ * 8 + 4];          \
        float p = w0.x*hB[0] + w0.y*hB[1] + w0.z*hB[2] + w0.w*hB[3]           \
                + w1.x*hB[4] + w1.y*hB[5] + w1.z*hB[6] + w1.w*hB[7]           \
                + w2.x*hB[8] + w2.y*hB[9] + w2.z*hB[10] + w2.w*hB[11]         \
                + w3.x*hB[12] + w3.y*hB[13] + w3.z*hB[14] + w3.w*hB[15];      \
        p += __shfl_xor(p, 16);                                               \
        p += __shfl_xor(p, 32);                                               \
        xt *= 2.0f * sigmoidf_(p + (BIAS));                                   \
    }

#define MOG_SCALE(WOFF, BOFF)                                                 \
    {                                                                         \
        _Pragma("unroll")                                                     \
        for (int kc = 0; kc < 2; ++kc) {                                      \
            _Pragma("unroll")                                                 \
            for (int q = 0; q < 2; ++q) {                                     \
                float4 w4 = *(const float4*)&mogf[(WOFF) + kc*32 + g_*8 + q*4]; \
                float4 b4 = *(const float4*)&mogf[(BOFF) + kc*32 + g_*8 + q*4]; \
                int bse = kc * 8 + q * 4;                                     \
                hB[bse+0] *= 2.0f * sigmoidf_(xt * w4.x + b4.x);              \
                hB[bse+1] *= 2.0f * sigmoidf_(xt * w4.y + b4.y);              \
                hB[bse+2] *= 2.0f * sigmoidf_(xt * w4.z + b4.z);              \
                hB[bse+3] *= 2.0f * sigmoidf_(xt * w4.w + b4.w);              \
            }                                                                 \
        }                                                                     \
    }

    #pragma unroll 1
    for (int t = 0; t < TSTEPS; ++t) {
        float xt = sXseq[t * 128 + myrow];   // broadcast ds_read_b32

        // ---- mogrifier (fp32) ----
        MOG_DOT(M0W, m0b_s)
        MOG_SCALE(M1W, M1B)
        MOG_DOT(M2W, m2b_s)
        MOG_SCALE(M3W, M3B)
        MOG_DOT(M4W, m4b_s)

        // ---- B-frags: h -> split bf16 ----
        union { bf16x8 v; unsigned u[4]; } bhi0, bhi1, blo0, blo1, bext;
        #pragma unroll
        for (int kc = 0; kc < 2; ++kc) {
            #pragma unroll
            for (int jp = 0; jp < 4; ++jp) {
                float a = hB[kc * 8 + 2 * jp], b = hB[kc * 8 + 2 * jp + 1];
                unsigned hi = cvt_pk_bf16(a, b);
                float ah = __uint_as_float(hi << 16);
                float bh = __uint_as_float(hi & 0xffff0000u);
                unsigned lo = cvt_pk_bf16(a - ah, b - bh);
                if (kc == 0) { bhi0.u[jp] = hi; blo0.u[jp] = lo; }
                else         { bhi1.u[jp] = hi; blo1.u[jp] = lo; }
            }
        }
        {   // ext B: j = {xt_hi, xt_lo, xt_hi, 1, 1, 0, 0, 0}
            unsigned xh = cvt_pk_bf16(xt, xt) & 0xffffu;
            float xl = xt - bfh((unsigned short)xh);
            unsigned xlp = cvt_pk_bf16(xl, xl) & 0xffffu;
            bext.u[0] = xh | (xlp << 16);
            bext.u[1] = xh | (0x3F80u << 16);
            bext.u[2] = 0x3F80u;
            bext.u[3] = 0u;
        }

        auto gate_tile = [&](int tt) -> f32x4 {
            bf16x8 whi0 = WA[(tt * 4 + 0) * 64 + lane];
            bf16x8 whi1 = WA[(tt * 4 + 1) * 64 + lane];
            bf16x8 wlo0 = WA[(tt * 4 + 2) * 64 + lane];
            bf16x8 wlo1 = WA[(tt * 4 + 3) * 64 + lane];
            bf16x8 wext = *(const bf16x8*)(extb + tt * extstep);
            f32x4 d = {0.0f, 0.0f, 0.0f, 0.0f};
            d = __builtin_amdgcn_mfma_f32_16x16x32_bf16(wext, bext.v, d, 0, 0, 0);
            d = __builtin_amdgcn_mfma_f32_16x16x32_bf16(whi0, bhi0.v, d, 0, 0, 0);
            d = __builtin_amdgcn_mfma_f32_16x16x32_bf16(whi1, bhi1.v, d, 0, 0, 0);
            d = __builtin_amdgcn_mfma_f32_16x16x32_bf16(whi0, blo0.v, d, 0, 0, 0);
            d = __builtin_amdgcn_mfma_f32_16x16x32_bf16(whi1, blo1.v, d, 0, 0, 0);
            d = __builtin_amdgcn_mfma_f32_16x16x32_bf16(wlo0, bhi0.v, d, 0, 0, 0);
            d = __builtin_amdgcn_mfma_f32_16x16x32_bf16(wlo1, bhi1.v, d, 0, 0, 0);
            return d;
        };

        // ---- half 1: gates i (tiles 0-3) and g (tiles 8-11) -> p1 ----
        f32x4 p1[4];
        {
            f32x4 acci[4], accg[4];
            #pragma unroll
            for (int u = 0; u < 4; ++u) { acci[u] = gate_tile(u); accg[u] = gate_tile(8 + u); }
            #pragma unroll
            for (int u = 0; u < 4; ++u)
                #pragma unroll
                for (int e = 0; e < 4; ++e)
                    p1[u][e] = sigmoidf_(acci[u][e]) * tanhf_(accg[u][e]);
        }

        // ---- half 2: gates f (tiles 4-7) and o (tiles 12-15) -> c, h ----
        float hn[4][4];
        {
            f32x4 accf[4], acco[4];
            #pragma unroll
            for (int u = 0; u < 4; ++u) { accf[u] = gate_tile(4 + u); acco[u] = gate_tile(12 + u); }
            #pragma unroll
            for (int u = 0; u < 4; ++u)
                #pragma unroll
                for (int e = 0; e < 4; ++e) {
                    float cc = sigmoidf_(accf[u][e]) * cst[u][e] + p1[u][e];
                    cst[u][e] = cc;
                    hn[u][e] = sigmoidf_(acco[u][e]) * tanhf_(cc);
                }
        }

        // ---- redistribute hn (unit 16u+4g+e, row n) -> hB (unit kc*32+8g+j) ----
        #pragma unroll
        for (int up = 0; up < 2; ++up) {
            #pragma unroll
            for (int e = 0; e < 4; ++e) {
                float send = glow ? hn[2 * up + 1][e] : hn[2 * up][e];
                float got = __shfl_xor(send, 32);
                hn[2 * up + 1][e] = glow ? got : hn[2 * up + 1][e];
                hn[2 * up][e]     = glow ? hn[2 * up][e] : got;
            }
        }
        #pragma unroll
        for (int up = 0; up < 2; ++up) {
            #pragma unroll
            for (int e = 0; e < 4; ++e) {
                float send = geven ? hn[2 * up + 1][e] : hn[2 * up][e];
                float got = __shfl_xor(send, 16);
                hn[2 * up + 1][e] = geven ? got : hn[2 * up + 1][e];
                hn[2 * up][e]     = geven ? hn[2 * up][e] : got;
            }
        }
        #pragma unroll
        for (int kc = 0; kc < 2; ++kc)
            #pragma unroll
            for (int j = 0; j < 8; ++j)
                hB[kc * 8 + j] = hn[2 * kc + (j >> 2)][j & 3];
    }

    // ===================== projection: out = h @ Wp^T + Bp =====================
    #pragma unroll
    for (int p = 0; p < 5; ++p) {
        float ap = 0.0f;
        #pragma unroll
        for (int kc = 0; kc < 2; ++kc) {
            #pragma unroll
            for (int q = 0; q < 2; ++q) {
                float4 w = *(const float4*)&mogf[WPo + p * 64 + kc * 32 + g_ * 8 + q * 4];
                ap += w.x * hB[kc * 8 + q * 4 + 0] + w.y * hB[kc * 8 + q * 4 + 1]
                    + w.z * hB[kc * 8 + q * 4 + 2] + w.w * hB[kc * 8 + q * 4 + 3];
            }
        }
        ap += __shfl_xor(ap, 16);
        ap += __shfl_xor(ap, 32);
        if (g_ == 0)
            out[(rowbase + myrow) * 5 + p] = ap + mogf[BPo + p];
    }
}

extern "C" void kernel_launch(void* const* d_in, const int* in_sizes, int n_in,
                              void* d_out, int out_size, void* d_ws, size_t ws_size,
                              hipStream_t stream) {
    const float* x   = (const float*)d_in[0];
    const float* W1  = (const float*)d_in[1];
    const float* B1  = (const float*)d_in[2];
    const float* W2  = (const float*)d_in[3];
    const float* B2  = (const float*)d_in[4];
    const float* W3  = (const float*)d_in[5];
    const float* B3  = (const float*)d_in[6];
    const float* W4  = (const float*)d_in[7];
    const float* B4  = (const float*)d_in[8];
    const float* M0w = (const float*)d_in[9];
    const float* M0b = (const float*)d_in[10];
    const float* M1w = (const float*)d_in[11];
    const float* M1b = (const float*)d_in[12];
    const float* M2w = (const float*)d_in[13];
    const float* M2b = (const float*)d_in[14];
    const float* M3w = (const float*)d_in[15];
    const float* M3b = (const float*)d_in[16];
    const float* M4w = (const float*)d_in[17];
    const float* M4b = (const float*)d_in[18];
    const float* Wih = (const float*)d_in[19];
    const float* Bih = (const float*)d_in[20];
    const float* Whh = (const float*)d_in[21];
    const float* Bhh = (const float*)d_in[22];
    const float* Wp  = (const float*)d_in[23];
    const float* Bp  = (const float*)d_in[24];

    int B = in_sizes[0] / HID;          // 262144
    int nblocks = B / ROWS_PB;          // 2048

    hipLaunchKernelGGL(moglstm_mfma4, dim3(nblocks), dim3(NTHREADS), 0, stream,
                       x, W1, B1, W2, B2, W3, B3, W4, B4,
                       M0w, M0b, M1w, M1b, M2w, M2b, M3w, M3b, M4w, M4b,
                       Wih, Bih, Whh, Bhh, Wp, Bp, (float*)d_out);
}